// Round 5
// baseline (238.222 us; speedup 1.0000x reference)
//
#include <hip/hip_runtime.h>

// VQ-VAE vector quantizer, round 5: split-bf16 MFMA, occupancy fix.
// Round 3/4 were latency-bound at 2 waves/SIMD (grid 512 blocks = 2 blk/CU). This round:
// 16 points/wave, NPB=64, grid 1024 -> 4 blk/CU x 4 waves = 4 waves/SIMD, VGPR capped 128.
// K-loop = 64 independent groups (16 codes, K=64 split hh+hl+lh = 6 MFMA chain), unroll 4
// for cross-group ILP; B frags straight from global (L1-hot 256 KB table), no barriers.
// Exact streaming top-2; near-ties (gap < 1e-3 vs ~1e-4 error bound) rescanned in fp32.
// out (fp32 concat): [ loss(1) | quantized NCHW (4194304) | indices as float (65536) ]

#define DIMS   64
#define HW     4096
#define NPTS   65536
#define NCODES 1024
#define NPB    64
#define QOFF   1
#define IOFF   (1 + NPTS * DIMS)
#define EPSGAP 1.0e-3f

typedef unsigned int uint;
typedef unsigned short ushort;
typedef unsigned long long ull;
typedef __attribute__((ext_vector_type(8))) short short8;
typedef __attribute__((ext_vector_type(4))) float f32x4;

__device__ __forceinline__ ushort bf16_rne(float f) {
    uint u = __float_as_uint(f);
    uint r = u + 0x7FFFu + ((u >> 16) & 1u);
    return (ushort)(r >> 16);
}
__device__ __forceinline__ float bf16f(ushort h) { return __uint_as_float(((uint)h) << 16); }

// ---- prep: emb fp32 -> {Eh, El bf16 [1024][64]}, hsq = 0.5||e||^2, and zero out[0]
__global__ void vq_prep(const float* __restrict__ emb, ushort* __restrict__ Eh,
                        ushort* __restrict__ El, float* __restrict__ hsq,
                        float* __restrict__ out)
{
    const int t = blockIdx.x * 256 + threadIdx.x;      // 0..16383, one float4 each
    if (t == 0) out[0] = 0.f;                          // loss accumulator (atomics later)
    float4 v = ((const float4*)emb)[t];
    ushort h0 = bf16_rne(v.x), h1 = bf16_rne(v.y), h2 = bf16_rne(v.z), h3 = bf16_rne(v.w);
    ushort l0 = bf16_rne(v.x - bf16f(h0)), l1 = bf16_rne(v.y - bf16f(h1));
    ushort l2 = bf16_rne(v.z - bf16f(h2)), l3 = bf16_rne(v.w - bf16f(h3));
    uint2 hp, lp;
    hp.x = (uint)h0 | ((uint)h1 << 16); hp.y = (uint)h2 | ((uint)h3 << 16);
    lp.x = (uint)l0 | ((uint)l1 << 16); lp.y = (uint)l2 | ((uint)l3 << 16);
    *(uint2*)(Eh + (size_t)t * 4) = hp;
    *(uint2*)(El + (size_t)t * 4) = lp;
    if (t < NCODES) {
        const float4* r = (const float4*)(emb + (size_t)t * DIMS);
        float s = 0.f;
        #pragma unroll
        for (int i = 0; i < 16; ++i) {
            float4 e = r[i];
            s = fmaf(e.x, e.x, s); s = fmaf(e.y, e.y, s);
            s = fmaf(e.z, e.z, s); s = fmaf(e.w, e.w, s);
        }
        hsq[t] = 0.5f * s;
    }
}

__launch_bounds__(256, 4)
__global__ void vq_main(const float* __restrict__ in, const float* __restrict__ emb,
                        const ushort* __restrict__ Ehw, const ushort* __restrict__ Elw,
                        const float* __restrict__ hsqw, float* __restrict__ out)
{
    // 16 KB: XH [0,8K) | XL [8K,16K); dead after A-frag load -> reused by epilogue
    __shared__ __align__(16) unsigned char smem[16384];

    const int tid = threadIdx.x;
    const int n0 = blockIdx.x * NPB;
    const int b = n0 >> 12, off = n0 & 4095;           // 64 | 4096: never crosses a batch
    const float* xbase = in + (size_t)b * (DIMS * HW) + off;

    // ---- stage X hi/lo bf16 into LDS [p][16B-unit u ^ (p&7)] (coalesced over p)
    {
        const int p = tid & 63, u0 = tid >> 6;         // u0 in 0..3
        const float* xp = xbase + p;
        #pragma unroll
        for (int t = 0; t < 2; ++t) {
            const int u = u0 + t * 4;                  // 16B-unit = 8 dims
            uint hp[4], lp[4];
            #pragma unroll
            for (int j2 = 0; j2 < 4; ++j2) {
                float a = xp[(u * 8 + j2 * 2 + 0) * HW];
                float c = xp[(u * 8 + j2 * 2 + 1) * HW];
                ushort ha = bf16_rne(a), hc = bf16_rne(c);
                ushort la = bf16_rne(a - bf16f(ha)), lc = bf16_rne(c - bf16f(hc));
                hp[j2] = (uint)ha | ((uint)hc << 16);
                lp[j2] = (uint)la | ((uint)lc << 16);
            }
            const int slot = (u ^ (p & 7)) * 16;
            *(uint4*)(smem + p * 128 + slot) = make_uint4(hp[0], hp[1], hp[2], hp[3]);
            *(uint4*)(smem + 8192 + p * 128 + slot) = make_uint4(lp[0], lp[1], lp[2], lp[3]);
        }
    }
    __syncthreads();

    const int lane = tid & 63, w = tid >> 6;
    const int m = lane & 15, quad = lane >> 4;

    // ---- A fragments: this wave's 16 points (hi+lo, K=64 in 2 steps), regs for whole kernel
    short8 Ah[2], Al[2];
    {
        const int p = w * 16 + m;
        #pragma unroll
        for (int ks = 0; ks < 2; ++ks) {
            const int u = ks * 4 + quad;
            const int a = p * 128 + ((u ^ (p & 7)) * 16);
            Ah[ks] = *(const short8*)(smem + a);
            Al[ks] = *(const short8*)(smem + 8192 + a);
        }
    }
    __syncthreads();   // X LDS dead for ALL waves beyond this point (epilogue overlays)

    float v1s[4], v2s[4]; int i1s[4];
    #pragma unroll
    for (int s = 0; s < 4; ++s) { v1s[s] = 1e30f; v2s[s] = 1e30f; i1s[s] = 0; }

    // ---- barrier-free K-loop: 64 groups of 16 codes; unroll 4 pipelines loads/MFMA chains
    #pragma unroll 4
    for (int g = 0; g < 64; ++g) {
        const int ca = g * 16 + m;                     // this lane's code id
        short8 Bh[2], Bl[2];
        #pragma unroll
        for (int ks = 0; ks < 2; ++ks) {
            const size_t ua = (size_t)ca * 64 + (ks * 4 + quad) * 8;
            Bh[ks] = *(const short8*)(Ehw + ua);
            Bl[ks] = *(const short8*)(Elw + ua);
        }
        const float ha = hsqw[ca];
        f32x4 acc = {0.f, 0.f, 0.f, 0.f};
        acc = __builtin_amdgcn_mfma_f32_16x16x32_bf16(Ah[0], Bh[0], acc, 0, 0, 0);
        acc = __builtin_amdgcn_mfma_f32_16x16x32_bf16(Ah[1], Bh[1], acc, 0, 0, 0);
        acc = __builtin_amdgcn_mfma_f32_16x16x32_bf16(Ah[0], Bl[0], acc, 0, 0, 0);
        acc = __builtin_amdgcn_mfma_f32_16x16x32_bf16(Ah[1], Bl[1], acc, 0, 0, 0);
        acc = __builtin_amdgcn_mfma_f32_16x16x32_bf16(Al[0], Bh[0], acc, 0, 0, 0);
        acc = __builtin_amdgcn_mfma_f32_16x16x32_bf16(Al[1], Bh[1], acc, 0, 0, 0);
        #pragma unroll
        for (int r = 0; r < 4; ++r) {                  // point = quad*4 + r
            float d = ha - acc[r];
            v2s[r] = fminf(v2s[r], fmaxf(d, v1s[r])); // exact streaming 2nd-min (v1 pre-update)
            bool c = d < v1s[r];                       // strict: ascending g keeps lowest code
            i1s[r] = c ? ca : i1s[r];
            v1s[r] = fminf(d, v1s[r]);
        }
    }

    // ---- merge states across the 16 code-columns (xor shuffle in 16-lane groups)
    #pragma unroll
    for (int st = 1; st < 16; st <<= 1) {
        #pragma unroll
        for (int s = 0; s < 4; ++s) {
            float ov1 = __shfl_xor(v1s[s], st);
            float ov2 = __shfl_xor(v2s[s], st);
            int   oi1 = __shfl_xor(i1s[s], st);
            v2s[s] = fminf(fminf(v2s[s], ov2), fmaxf(v1s[s], ov1));
            bool c = (ov1 < v1s[s]) || (ov1 == v1s[s] && oi1 < i1s[s]);
            if (c) i1s[s] = oi1;
            v1s[s] = fminf(v1s[s], ov1);
        }
    }

    // epilogue scratch overlays dead X region
    float* pv1 = (float*)smem;                         // [64]
    int*   pi1 = (int*)(smem + 256);                   // [64]
    float* pv2 = (float*)(smem + 512);                 // [64]
    ull*   msk = (ull*)(smem + 768);                   // [1]
    int*   lst = (int*)(smem + 784);                   // [0]=cnt, entries at +1

    if (m == 0) {
        #pragma unroll
        for (int s = 0; s < 4; ++s) {
            int p = w * 16 + quad * 4 + s;
            pv1[p] = v1s[s]; pi1[p] = i1s[s]; pv2[p] = v2s[s];
        }
    }
    __syncthreads();

    {
        bool f = (tid < NPB) && ((pv2[tid] - pv1[tid]) < EPSGAP);
        ull bm = __ballot(f);
        if (tid == 0) msk[0] = bm;                     // wave 0 covers all 64 points
    }
    __syncthreads();
    if (tid == 0) {
        int c = 0;
        ull m0 = msk[0];
        while (m0) { lst[1 + c++] = __ffsll(m0) - 1; m0 &= m0 - 1; }
        lst[0] = c;
    }
    __syncthreads();

    // ---- exact fp32 rescan, one wave per flagged point (rare: gap < 1e-3)
    const int cnt = lst[0];
    for (int it = w; it < cnt; it += 4) {
        const int p = lst[1 + it];
        float xv = xbase[lane * HW + p];               // lane d holds x_d (exact fp32)
        float acc[16];
        #pragma unroll
        for (int j = 0; j < 16; ++j) acc[j] = 0.f;
        #pragma unroll 4
        for (int d4 = 0; d4 < 16; ++d4) {
            float x0 = __shfl(xv, d4 * 4 + 0), x1 = __shfl(xv, d4 * 4 + 1);
            float x2 = __shfl(xv, d4 * 4 + 2), x3 = __shfl(xv, d4 * 4 + 3);
            #pragma unroll
            for (int j = 0; j < 16; ++j) {
                const int k = lane + 64 * j;
                float4 e = *(const float4*)(emb + (size_t)k * DIMS + d4 * 4);
                acc[j] = fmaf(x0, e.x, acc[j]); acc[j] = fmaf(x1, e.y, acc[j]);
                acc[j] = fmaf(x2, e.z, acc[j]); acc[j] = fmaf(x3, e.w, acc[j]);
            }
        }
        float bv = 1e30f; int bk = 0;
        #pragma unroll
        for (int j = 0; j < 16; ++j) {                 // ascending k per lane: first-min kept
            const int k = lane + 64 * j;
            float v = hsqw[k] - acc[j];
            if (v < bv) { bv = v; bk = k; }
        }
        #pragma unroll
        for (int st = 32; st; st >>= 1) {              // 64-wide (v, k) argmin, k tie-break
            float ov = __shfl_xor(bv, st);
            int   ok = __shfl_xor(bk, st);
            if (ov < bv || (ov == bv && ok < bk)) { bv = ov; bk = ok; }
        }
        if (lane == 0) pi1[p] = bk;
    }
    __syncthreads();

    // ---- final: indices, quantized gather-write, loss (wave 0, one point per lane)
    if (tid < NPB) {
        const int p = tid;
        const int bi = pi1[p];
        out[IOFF + n0 + p] = (float)bi;
        const float* e = emb + (size_t)bi * DIMS;
        const float* xp = xbase + p;
        float* oq = out + QOFF + (size_t)b * (DIMS * HW) + off + p;
        float ls = 0.f;
        #pragma unroll 8
        for (int d = 0; d < DIMS; ++d) {
            float ev = e[d];
            float xv = xp[d * HW];
            float df = ev - xv;
            ls = fmaf(df, df, ls);
            oq[d * HW] = ev;                           // coalesced across point-threads
        }
        #pragma unroll
        for (int st = 32; st; st >>= 1) ls += __shfl_down(ls, st);
        if (lane == 0) atomicAdd(out, ls * (0.25f / (float)(NPTS * DIMS)));
    }
}

extern "C" void kernel_launch(void* const* d_in, const int* in_sizes, int n_in,
                              void* d_out, int out_size, void* d_ws, size_t ws_size,
                              hipStream_t stream) {
    const float* in  = (const float*)d_in[0];
    const float* emb = (const float*)d_in[1];
    float* out = (float*)d_out;
    ushort* Eh = (ushort*)d_ws;                        // 131072 B
    ushort* El = (ushort*)((char*)d_ws + 131072);      // 131072 B
    float*  hsq = (float*)((char*)d_ws + 262144);      // 4096 B
    (void)in_sizes; (void)n_in; (void)out_size; (void)ws_size;

    vq_prep<<<64, 256, 0, stream>>>(emb, Eh, El, hsq, out);   // also zeroes out[0]
    vq_main<<<NPTS / NPB, 256, 0, stream>>>(in, emb, Eh, El, hsq, out);
}

// Round 6
// 179.318 us; speedup vs baseline: 1.3285x; 1.3285x over previous
//
#include <hip/hip_runtime.h>

// VQ-VAE vector quantizer, round 6: split-bf16 MFMA, NO workspace.
// Rounds 3-5 all ran ~7x slower than issue/BW models while streaming the code table from
// d_ws; theory: d_ws is not L2-cached (fine-grained MTYPE) -> every table load pays
// HBM/L3-class latency. This round sources everything from d_in (emb/in, known-cached):
// per-chunk fp32->hi/lo bf16 conversion into LDS, hsq via shuffle tree, A-frags direct
// from global. NPB=64, grid 1024 -> 4 blocks/CU x 4 waves = 4 waves/SIMD, ~80 VGPR, no spills.
// Exact streaming top-2; near-ties (gap < 1e-3 vs ~2e-4 worst-case split error) rescanned
// in fp32 (dot and ||e||^2 recomputed inline from emb).
// out (fp32 concat): [ loss(1) | quantized NCHW (4194304) | indices as float (65536) ]

#define DIMS   64
#define HW     4096
#define NPTS   65536
#define NCODES 1024
#define NPB    64
#define QOFF   1
#define IOFF   (1 + NPTS * DIMS)
#define EPSGAP 1.0e-3f

typedef unsigned int uint;
typedef unsigned short ushort;
typedef unsigned long long ull;
typedef __attribute__((ext_vector_type(8))) short short8;
typedef __attribute__((ext_vector_type(4))) float f32x4;

__device__ __forceinline__ ushort bf16_rne(float f) {
    uint u = __float_as_uint(f);
    uint r = u + 0x7FFFu + ((u >> 16) & 1u);
    return (ushort)(r >> 16);
}
__device__ __forceinline__ float bf16f(ushort h) { return __uint_as_float(((uint)h) << 16); }

__launch_bounds__(256, 4)
__global__ void vq_main(const float* __restrict__ in, const float* __restrict__ emb,
                        float* __restrict__ out)
{
    // Eh [0,8K) | El [8K,16K) | hsqc [16K,16K+256) ; Eh region overlaid by epilogue scratch
    __shared__ __align__(16) unsigned char smem[16640];
    unsigned char* EhL = smem;
    unsigned char* ElL = smem + 8192;
    float* hsqc = (float*)(smem + 16384);

    const int tid = threadIdx.x;
    const int lane = tid & 63, w = tid >> 6;
    const int m = lane & 15, quad = lane >> 4;
    const int n0 = blockIdx.x * NPB;
    const int b = n0 >> 12, off = n0 & 4095;           // 64 | 4096: never crosses a batch
    const float* xbase = in + (size_t)b * (DIMS * HW) + off;
    const float4* e4 = (const float4*)emb;

    // ---- A fragments straight from global (cached), converted to hi/lo bf16 in regs
    short8 Ah[2], Al[2];
    {
        const int p = w * 16 + m;
        #pragma unroll
        for (int ks = 0; ks < 2; ++ks) {
            union { ushort u[8]; short8 v; } th, tl;
            #pragma unroll
            for (int j = 0; j < 8; ++j) {
                float x = xbase[(ks * 32 + quad * 8 + j) * HW + p];
                ushort h = bf16_rne(x);
                th.u[j] = h;
                tl.u[j] = bf16_rne(x - bf16f(h));
            }
            Ah[ks] = th.v; Al[ks] = tl.v;
        }
    }

    float v1s[4], v2s[4]; int i1s[4];
    #pragma unroll
    for (int s = 0; s < 4; ++s) { v1s[s] = 1e30f; v2s[s] = 1e30f; i1s[s] = 0; }

    // ---- K-loop: 16 chunks of 64 codes, staged fp32->split-bf16 from cached emb
    for (int ch = 0; ch < 16; ++ch) {
        #pragma unroll
        for (int t = 0; t < 4; ++t) {                  // 1024 float4 per chunk, 4/thread
            const int idx = tid + t * 256;
            const int c = idx >> 4, s = idx & 15;      // code 0..63, float4-slot 0..15
            float4 v = e4[ch * 1024 + idx];
            ushort h0 = bf16_rne(v.x), h1 = bf16_rne(v.y), h2 = bf16_rne(v.z), h3 = bf16_rne(v.w);
            ushort l0 = bf16_rne(v.x - bf16f(h0)), l1 = bf16_rne(v.y - bf16f(h1));
            ushort l2 = bf16_rne(v.z - bf16f(h2)), l3 = bf16_rne(v.w - bf16f(h3));
            uint2 hp, lp;
            hp.x = (uint)h0 | ((uint)h1 << 16); hp.y = (uint)h2 | ((uint)h3 << 16);
            lp.x = (uint)l0 | ((uint)l1 << 16); lp.y = (uint)l2 | ((uint)l3 << 16);
            const int daddr = c * 128 + (((s >> 1) ^ (c & 7)) * 16) + (s & 1) * 8;
            *(uint2*)(EhL + daddr) = hp;
            *(uint2*)(ElL + daddr) = lp;
            // ||e||^2: 16 consecutive lanes hold the 16 slots of code c -> shuffle tree
            float pe = fmaf(v.x, v.x, fmaf(v.y, v.y, fmaf(v.z, v.z, v.w * v.w)));
            pe += __shfl_xor(pe, 1); pe += __shfl_xor(pe, 2);
            pe += __shfl_xor(pe, 4); pe += __shfl_xor(pe, 8);
            if (s == 0) hsqc[c] = 0.5f * pe;
        }
        __syncthreads();

        float hv[4];
        #pragma unroll
        for (int g = 0; g < 4; ++g) hv[g] = hsqc[g * 16 + m];

        #pragma unroll
        for (int g = 0; g < 4; ++g) {
            const int row = g * 16 + m;                // code within chunk
            const int ca = ch * 64 + row;              // absolute code id
            short8 Bh[2], Bl[2];
            #pragma unroll
            for (int ks = 0; ks < 2; ++ks) {
                const int a = row * 128 + (((ks * 4 + quad) ^ (row & 7)) * 16);
                Bh[ks] = *(const short8*)(EhL + a);
                Bl[ks] = *(const short8*)(ElL + a);
            }
            f32x4 acc = {0.f, 0.f, 0.f, 0.f};
            acc = __builtin_amdgcn_mfma_f32_16x16x32_bf16(Ah[0], Bh[0], acc, 0, 0, 0);
            acc = __builtin_amdgcn_mfma_f32_16x16x32_bf16(Ah[1], Bh[1], acc, 0, 0, 0);
            acc = __builtin_amdgcn_mfma_f32_16x16x32_bf16(Ah[0], Bl[0], acc, 0, 0, 0);
            acc = __builtin_amdgcn_mfma_f32_16x16x32_bf16(Ah[1], Bl[1], acc, 0, 0, 0);
            acc = __builtin_amdgcn_mfma_f32_16x16x32_bf16(Al[0], Bh[0], acc, 0, 0, 0);
            acc = __builtin_amdgcn_mfma_f32_16x16x32_bf16(Al[1], Bh[1], acc, 0, 0, 0);
            #pragma unroll
            for (int r = 0; r < 4; ++r) {              // point = quad*4 + r
                float d = hv[g] - acc[r];
                v2s[r] = fminf(v2s[r], fmaxf(d, v1s[r]));   // exact streaming 2nd-min
                bool c2 = d < v1s[r];                  // strict: ascending ca keeps lowest idx
                i1s[r] = c2 ? ca : i1s[r];
                v1s[r] = fminf(d, v1s[r]);
            }
        }
        __syncthreads();
    }

    // ---- merge states across the 16 code-lanes (xor shuffle within 16-lane groups)
    #pragma unroll
    for (int st = 1; st < 16; st <<= 1) {
        #pragma unroll
        for (int s = 0; s < 4; ++s) {
            float ov1 = __shfl_xor(v1s[s], st);
            float ov2 = __shfl_xor(v2s[s], st);
            int   oi1 = __shfl_xor(i1s[s], st);
            v2s[s] = fminf(fminf(v2s[s], ov2), fmaxf(v1s[s], ov1));
            bool c = (ov1 < v1s[s]) || (ov1 == v1s[s] && oi1 < i1s[s]);
            if (c) i1s[s] = oi1;
            v1s[s] = fminf(v1s[s], ov1);
        }
    }

    // epilogue scratch overlays dead Eh region (final barrier above was end of K-loop)
    float* pv1 = (float*)smem;                         // [64]
    int*   pi1 = (int*)(smem + 256);                   // [64]
    float* pv2 = (float*)(smem + 512);                 // [64]
    ull*   msk = (ull*)(smem + 768);                   // [1]
    int*   lst = (int*)(smem + 776);                   // [0]=cnt, entries at +1

    if (m == 0) {
        #pragma unroll
        for (int s = 0; s < 4; ++s) {
            int p = w * 16 + quad * 4 + s;
            pv1[p] = v1s[s]; pi1[p] = i1s[s]; pv2[p] = v2s[s];
        }
    }
    __syncthreads();

    {
        bool f = (tid < NPB) && ((pv2[tid] - pv1[tid]) < EPSGAP);
        ull bm = __ballot(f);
        if (tid == 0) msk[0] = bm;                     // wave 0's lanes cover all 64 points
    }
    __syncthreads();
    if (tid == 0) {
        int c = 0;
        ull m0 = msk[0];
        while (m0) { lst[1 + c++] = __ffsll(m0) - 1; m0 &= m0 - 1; }
        lst[0] = c;
    }
    __syncthreads();

    // ---- exact fp32 rescan, one wave per flagged point (dot and ||e||^2 from cached emb)
    const int cnt = lst[0];
    for (int it = w; it < cnt; it += 4) {
        const int p = lst[1 + it];
        float xv = xbase[lane * HW + p];               // lane d holds x_d (exact fp32)
        float dacc[16], eacc[16];
        #pragma unroll
        for (int j = 0; j < 16; ++j) { dacc[j] = 0.f; eacc[j] = 0.f; }
        #pragma unroll 4
        for (int d4 = 0; d4 < 16; ++d4) {
            float x0 = __shfl(xv, d4 * 4 + 0), x1 = __shfl(xv, d4 * 4 + 1);
            float x2 = __shfl(xv, d4 * 4 + 2), x3 = __shfl(xv, d4 * 4 + 3);
            #pragma unroll
            for (int j = 0; j < 16; ++j) {
                const int k = lane + 64 * j;
                float4 e = e4[k * 16 + d4];
                dacc[j] = fmaf(x0, e.x, dacc[j]); dacc[j] = fmaf(x1, e.y, dacc[j]);
                dacc[j] = fmaf(x2, e.z, dacc[j]); dacc[j] = fmaf(x3, e.w, dacc[j]);
                eacc[j] = fmaf(e.x, e.x, eacc[j]); eacc[j] = fmaf(e.y, e.y, eacc[j]);
                eacc[j] = fmaf(e.z, e.z, eacc[j]); eacc[j] = fmaf(e.w, e.w, eacc[j]);
            }
        }
        float bv = 1e30f; int bk = 0;
        #pragma unroll
        for (int j = 0; j < 16; ++j) {                 // ascending k per lane: first-min kept
            const int k = lane + 64 * j;
            float v = fmaf(0.5f, eacc[j], -dacc[j]);
            if (v < bv) { bv = v; bk = k; }
        }
        #pragma unroll
        for (int st = 32; st; st >>= 1) {              // 64-wide (v, k) argmin, k tie-break
            float ov = __shfl_xor(bv, st);
            int   ok = __shfl_xor(bk, st);
            if (ov < bv || (ov == bv && ok < bk)) { bv = ov; bk = ok; }
        }
        if (lane == 0) pi1[p] = bk;
    }
    __syncthreads();

    // ---- final: indices, quantized gather-write, loss (wave 0, one point per lane)
    if (tid < NPB) {
        const int p = tid;
        const int bi = pi1[p];
        out[IOFF + n0 + p] = (float)bi;
        const float* e = emb + (size_t)bi * DIMS;
        const float* xp = xbase + p;
        float* oq = out + QOFF + (size_t)b * (DIMS * HW) + off + p;
        float ls = 0.f;
        #pragma unroll 8
        for (int d = 0; d < DIMS; ++d) {
            float ev = e[d];
            float xv = xp[d * HW];
            float df = ev - xv;
            ls = fmaf(df, df, ls);
            oq[d * HW] = ev;                           // coalesced across point-threads
        }
        #pragma unroll
        for (int st = 32; st; st >>= 1) ls += __shfl_down(ls, st);
        if (lane == 0) atomicAdd(out, ls * (0.25f / (float)(NPTS * DIMS)));
    }
}

extern "C" void kernel_launch(void* const* d_in, const int* in_sizes, int n_in,
                              void* d_out, int out_size, void* d_ws, size_t ws_size,
                              hipStream_t stream) {
    const float* in  = (const float*)d_in[0];
    const float* emb = (const float*)d_in[1];
    float* out = (float*)d_out;
    (void)d_ws; (void)ws_size; (void)in_sizes; (void)n_in; (void)out_size;

    hipMemsetAsync(d_out, 0, sizeof(float), stream);   // loss accumulated via atomics
    vq_main<<<NPTS / NPB, 256, 0, stream>>>(in, emb, out);
}